// Round 10
// baseline (2351.471 us; speedup 1.0000x reference)
//
#include <hip/hip_runtime.h>
#include <math.h>

// ---------- helpers ----------
__device__ __forceinline__ float wsum64(float v) {
#pragma unroll
  for (int m = 32; m > 0; m >>= 1) v += __shfl_xor(v, m, 64);
  return v;
}
__device__ __forceinline__ float silu_f(float x) { return x / (1.0f + __expf(-x)); }

// LayerNorm across a 64-lane wave (one value per lane), eps=1e-5
__device__ __forceinline__ float ln64(float v, float g, float b) {
  float s  = wsum64(v);
  float s2 = wsum64(v * v);
  float m   = s * 0.015625f;                       // /64
  float var = fmaxf(s2 * 0.015625f - m * m, 0.0f);
  return (v - m) * rsqrtf(var + 1e-5f) * g + b;
}

// ---------- node embedding: h = silu(LN(x @ ne_w + ne_b)) ----------
__global__ __launch_bounds__(256) void k_node_embed(
    const float* __restrict__ x, const float* __restrict__ W,
    const float* __restrict__ b, const float* __restrict__ g,
    const float* __restrict__ be, float* __restrict__ h, int n) {
  int row = (blockIdx.x * 256 + threadIdx.x) >> 6;
  int j = threadIdx.x & 63;
  if (row >= n) return;
  const float* xr = x + (size_t)row * 16;
  float acc = b[j];
#pragma unroll
  for (int k = 0; k < 16; k += 4) {
    float4 xv = *(const float4*)&xr[k];
    acc += xv.x * W[(k + 0) * 64 + j] + xv.y * W[(k + 1) * 64 + j] +
           xv.z * W[(k + 2) * 64 + j] + xv.w * W[(k + 3) * 64 + j];
  }
  float v = ln64(acc, g[j], be[j]);
  h[(size_t)row * 64 + j] = silu_f(v);
}

// ---------- edge embedding (ONCE, layer-independent): ebuf = silu(LN(ea@eeW)) ----------
__global__ __launch_bounds__(256) void k_edge_embed(
    const float* __restrict__ ea, const float* __restrict__ eeW,
    const float* __restrict__ eeB, const float* __restrict__ eeG,
    const float* __restrict__ eeBe, float* __restrict__ ebuf, int nedges) {
  __shared__ float sEA[4][32];         // per-wave 4 edges x 8 attrs

  const int wv = threadIdx.x >> 6;
  const int j  = threadIdx.x & 63;
  const int ebase = (blockIdx.x * 4 + wv) * 4;
  if (ebase >= nedges) return;

  if (j < 32) {
    long long gi = (long long)ebase * 8 + j;
    long long gmax = (long long)nedges * 8 - 1;
    if (gi > gmax) gi = gmax;
    sEA[wv][j] = ea[gi];               // same-wave write->read: ordered
  }

  float ewc[8];
#pragma unroll
  for (int k = 0; k < 8; ++k) ewc[k] = eeW[k * 64 + j];
  const float eb = eeB[j], eg = eeG[j], ebe = eeBe[j];

#pragma unroll
  for (int e = 0; e < 4; ++e) {
    const float* ar = &sEA[wv][e * 8];
    float ev = eb;
#pragma unroll
    for (int k = 0; k < 8; ++k) ev += ar[k] * ewc[k];
    ev = silu_f(ln64(ev, eg, ebe));
    if (ebase + e < nedges) ebuf[(size_t)(ebase + e) * 64 + j] = ev;
  }
}

// ---------- edge message (pre-embedded path): no LDS, no barriers ----------
// m = LN(silu(hw1[dst] + hw2[src] + e@W3 + msg_b)); agg[dst] += m
#define EPW 4
__global__ __launch_bounds__(256) void k_edge_msg_pre(
    const float* __restrict__ ebuf, const float* __restrict__ W3,
    const float* __restrict__ msgB, const float* __restrict__ msgG,
    const float* __restrict__ msgBe,
    const float* __restrict__ hw1, const float* __restrict__ hw2,
    const int* __restrict__ srcI, const int* __restrict__ dstI,
    float* __restrict__ agg, int nedges) {
  const int wv = threadIdx.x >> 6;
  const int j  = threadIdx.x & 63;
  const int ebase = (blockIdx.x * 4 + wv) * EPW;
  if (ebase >= nedges) return;

  // long-latency gathers first
  const float bj = msgB[j];
  int dIdx[EPW];
  float acc[EPW];
#pragma unroll
  for (int e = 0; e < EPW; ++e) {
    int ce = min(ebase + e, nedges - 1);
    int s = srcI[ce];
    dIdx[e] = dstI[ce];
    acc[e] = hw1[(size_t)dIdx[e] * 64 + j] + hw2[(size_t)s * 64 + j] + bj;
  }

  // e-row base pointers (wave-uniform -> scalar-cache eligible broadcasts)
  const float* er0 = ebuf + (size_t)min(ebase + 0, nedges - 1) * 64;
  const float* er1 = ebuf + (size_t)min(ebase + 1, nedges - 1) * 64;
  const float* er2 = ebuf + (size_t)min(ebase + 2, nedges - 1) * 64;
  const float* er3 = ebuf + (size_t)min(ebase + 3, nedges - 1) * 64;

  // MAC: acc[e] += e_vec @ W3 ; W3 coalesced from global (L1-resident 16 KB)
#pragma unroll
  for (int k = 0; k < 64; k += 4) {
    float w0 = W3[(k + 0) * 64 + j];
    float w1 = W3[(k + 1) * 64 + j];
    float w2 = W3[(k + 2) * 64 + j];
    float w3 = W3[(k + 3) * 64 + j];
    float4 v0 = *(const float4*)&er0[k];
    float4 v1 = *(const float4*)&er1[k];
    float4 v2 = *(const float4*)&er2[k];
    float4 v3 = *(const float4*)&er3[k];
    acc[0] += v0.x * w0 + v0.y * w1 + v0.z * w2 + v0.w * w3;
    acc[1] += v1.x * w0 + v1.y * w1 + v1.z * w2 + v1.w * w3;
    acc[2] += v2.x * w0 + v2.y * w1 + v2.z * w2 + v2.w * w3;
    acc[3] += v3.x * w0 + v3.y * w1 + v3.z * w2 + v3.w * w3;
  }

  // LN + silu + scatter-add
  const float mg = msgG[j], mbe = msgBe[j];
#pragma unroll
  for (int e = 0; e < EPW; ++e) {
    float m = ln64(silu_f(acc[e]), mg, mbe);
    if (ebase + e < nedges) unsafeAtomicAdd(&agg[(size_t)dIdx[e] * 64 + j], m);
  }
}

// ---------- edge message FALLBACK (ws too small): r9 proven kernel ----------
__global__ __launch_bounds__(256) void k_edge_msg_fb(
    const float* __restrict__ ea, const float* __restrict__ eeW,
    const float* __restrict__ eeB, const float* __restrict__ eeG,
    const float* __restrict__ eeBe,
    const float* __restrict__ W3, const float* __restrict__ msgB,
    const float* __restrict__ msgG, const float* __restrict__ msgBe,
    const float* __restrict__ hw1, const float* __restrict__ hw2,
    const int* __restrict__ srcI, const int* __restrict__ dstI,
    float* __restrict__ agg, int nedges) {
  __shared__ float sE[4][EPW][64];
  __shared__ float sEA[4][EPW * 8];

  const int wv = threadIdx.x >> 6;
  const int j  = threadIdx.x & 63;
  const int ebase = (blockIdx.x * 4 + wv) * EPW;
  if (ebase >= nedges) return;

  if (j < 32) {
    long long gi = (long long)ebase * 8 + j;
    long long gmax = (long long)nedges * 8 - 1;
    if (gi > gmax) gi = gmax;
    sEA[wv][j] = ea[gi];
  }

  const float bj = msgB[j];
  int dIdx[EPW];
  float acc[EPW];
#pragma unroll
  for (int e = 0; e < EPW; ++e) {
    int ce = min(ebase + e, nedges - 1);
    int s = srcI[ce];
    dIdx[e] = dstI[ce];
    acc[e] = hw1[(size_t)dIdx[e] * 64 + j] + hw2[(size_t)s * 64 + j] + bj;
  }
  {
    float ewc[8];
#pragma unroll
    for (int k = 0; k < 8; ++k) ewc[k] = eeW[k * 64 + j];
    const float eb = eeB[j], eg = eeG[j], ebe = eeBe[j];
#pragma unroll
    for (int e = 0; e < EPW; ++e) {
      const float* ar = &sEA[wv][e * 8];
      float ev = eb;
#pragma unroll
      for (int k = 0; k < 8; ++k) ev += ar[k] * ewc[k];
      ev = silu_f(ln64(ev, eg, ebe));
      sE[wv][e][j] = ev;
    }
  }
#pragma unroll
  for (int k = 0; k < 64; k += 4) {
    float w0 = W3[(k + 0) * 64 + j];
    float w1 = W3[(k + 1) * 64 + j];
    float w2 = W3[(k + 2) * 64 + j];
    float w3 = W3[(k + 3) * 64 + j];
#pragma unroll
    for (int e = 0; e < EPW; ++e) {
      float4 ev4 = *(const float4*)&sE[wv][e][k];
      acc[e] += ev4.x * w0 + ev4.y * w1 + ev4.z * w2 + ev4.w * w3;
    }
  }
  const float mg = msgG[j], mbe = msgBe[j];
#pragma unroll
  for (int e = 0; e < EPW; ++e) {
    float m = ln64(silu_f(acc[e]), mg, mbe);
    if (ebase + e < nedges) unsafeAtomicAdd(&agg[(size_t)dIdx[e] * 64 + j], m);
  }
}

// ---------- per-node msg weights: hw1 = h@W[0:64], hw2 = h@W[64:128] ----------
__global__ __launch_bounds__(256) void k_node_msgw(
    const float* __restrict__ h, const float* __restrict__ W,
    float* __restrict__ hw1, float* __restrict__ hw2, int n) {
  int row = (blockIdx.x * 256 + threadIdx.x) >> 6;
  int j = threadIdx.x & 63;
  if (row >= n) return;
  const float* hr = h + (size_t)row * 64;
  float a1 = 0.0f, a2 = 0.0f;
#pragma unroll
  for (int k = 0; k < 64; k += 4) {
    float4 hv = *(const float4*)&hr[k];
    a1 += hv.x * W[(k + 0) * 64 + j] + hv.y * W[(k + 1) * 64 + j] +
          hv.z * W[(k + 2) * 64 + j] + hv.w * W[(k + 3) * 64 + j];
    a2 += hv.x * W[(64 + k + 0) * 64 + j] + hv.y * W[(64 + k + 1) * 64 + j] +
          hv.z * W[(64 + k + 2) * 64 + j] + hv.w * W[(64 + k + 3) * 64 + j];
  }
  hw1[(size_t)row * 64 + j] = a1;
  hw2[(size_t)row * 64 + j] = a2;
}

// ---------- update IN-PLACE: h = LN(LN(silu((h+agg)@W+b)) + h) ----------
// Safe: wave reads its whole row (lockstep wave-instructions) before the store;
// each row is touched by exactly one wave. No __restrict__ on h (aliased rd/wr).
__global__ __launch_bounds__(256) void k_node_update_ip(
    float* h, const float* __restrict__ agg,
    const float* __restrict__ W, const float* __restrict__ b,
    const float* __restrict__ ug, const float* __restrict__ ube,
    const float* __restrict__ ng, const float* __restrict__ nbe, int n) {
  int row = (blockIdx.x * 256 + threadIdx.x) >> 6;
  int j = threadIdx.x & 63;
  if (row >= n) return;
  float* hr = h + (size_t)row * 64;
  const float* ar = agg + (size_t)row * 64;
  float acc = b[j];
  float hj = hr[j];
#pragma unroll
  for (int k = 0; k < 64; k += 4) {
    float4 hv = *(const float4*)&hr[k];
    float4 av = *(const float4*)&ar[k];
    acc += (hv.x + av.x) * W[(k + 0) * 64 + j] + (hv.y + av.y) * W[(k + 1) * 64 + j] +
           (hv.z + av.z) * W[(k + 2) * 64 + j] + (hv.w + av.w) * W[(k + 3) * 64 + j];
  }
  float u = ln64(silu_f(acc), ug[j], ube[j]);
  hr[j] = ln64(u + hj, ng[j], nbe[j]);
}

// ---------- pooling ----------
__global__ __launch_bounds__(256) void k_pool(
    const float* __restrict__ h, const int* __restrict__ batch,
    float* __restrict__ gsum, float* __restrict__ gcnt, int n) {
  int row = (blockIdx.x * 256 + threadIdx.x) >> 6;
  int j = threadIdx.x & 63;
  if (row >= n) return;
  int b = batch[row];
  unsafeAtomicAdd(&gsum[(size_t)b * 64 + j], h[(size_t)row * 64 + j]);
  if (j == 0) unsafeAtomicAdd(&gcnt[b], 1.0f);
}

// ---------- head: out = silu(LN(g@h1_w+b)) @ h2_w + h2_b ----------
__global__ __launch_bounds__(64) void k_head(
    const float* __restrict__ gsum, const float* __restrict__ gcnt,
    const float* __restrict__ w1, const float* __restrict__ b1,
    const float* __restrict__ g1, const float* __restrict__ be1,
    const float* __restrict__ w2, const float* __restrict__ b2,
    float* __restrict__ out, int ngraphs) {
  int gidx = blockIdx.x;
  int j = threadIdx.x;
  if (gidx >= ngraphs) return;
  __shared__ float sg[64];
  float cnt = fmaxf(gcnt[gidx], 1.0f);
  sg[j] = gsum[(size_t)gidx * 64 + j] / cnt;
  float acc = 0.0f;
  if (j < 32) {
    acc = b1[j];
#pragma unroll 8
    for (int k = 0; k < 64; ++k) acc += sg[k] * w1[k * 32 + j];
  }
  float s = acc, s2 = acc * acc;
#pragma unroll
  for (int m = 16; m > 0; m >>= 1) {
    s  += __shfl_xor(s,  m, 64);
    s2 += __shfl_xor(s2, m, 64);
  }
  float mean = s * 0.03125f;
  float var  = fmaxf(s2 * 0.03125f - mean * mean, 0.0f);
  float z = 0.0f;
  if (j < 32) {
    float nv = (acc - mean) * rsqrtf(var + 1e-5f) * g1[j] + be1[j];
    z = silu_f(nv) * w2[j];
  }
  float tot = wsum64(z);
  if (j == 0) out[gidx] = tot + b2[0];
}

// ---------- launch ----------
extern "C" void kernel_launch(void* const* d_in, const int* in_sizes, int n_in,
                              void* d_out, int out_size, void* d_ws, size_t ws_size,
                              hipStream_t stream) {
  const float* x      = (const float*)d_in[0];
  const float* ea     = (const float*)d_in[1];
  const float* ne_w   = (const float*)d_in[2];
  const float* ne_b   = (const float*)d_in[3];
  const float* ne_g   = (const float*)d_in[4];
  const float* ne_be  = (const float*)d_in[5];
  const float* ee_w   = (const float*)d_in[6];
  const float* ee_b   = (const float*)d_in[7];
  const float* ee_g   = (const float*)d_in[8];
  const float* ee_be  = (const float*)d_in[9];
  const float* msg_w  = (const float*)d_in[10];
  const float* msg_b  = (const float*)d_in[11];
  const float* msg_g  = (const float*)d_in[12];
  const float* msg_be = (const float*)d_in[13];
  const float* upd_w  = (const float*)d_in[14];
  const float* upd_b  = (const float*)d_in[15];
  const float* upd_g  = (const float*)d_in[16];
  const float* upd_be = (const float*)d_in[17];
  const float* nrm_g  = (const float*)d_in[18];
  const float* nrm_be = (const float*)d_in[19];
  const float* h1_w   = (const float*)d_in[20];
  const float* h1_b   = (const float*)d_in[21];
  const float* h1_g   = (const float*)d_in[22];
  const float* h1_be  = (const float*)d_in[23];
  const float* h2_w   = (const float*)d_in[24];
  const float* h2_b   = (const float*)d_in[25];
  const int*   ei     = (const int*)d_in[26];
  const int*   batch  = (const int*)d_in[27];
  float* out = (float*)d_out;

  const int N = in_sizes[0] / 16;
  const int E = in_sizes[1] / 8;
  const int G = out_size;
  const int* srcI = ei;       // edge_index[0] = src (x_j)
  const int* dstI = ei + E;   // edge_index[1] = dst (x_i)

  float* ws  = (float*)d_ws;
  float* h    = ws;
  float* hw1  = h   + (size_t)N * 64;
  float* hw2  = hw1 + (size_t)N * 64;
  float* agg  = hw2 + (size_t)N * 64;
  float* gsum = agg + (size_t)N * 64;
  float* gcnt = gsum + (size_t)G * 64;
  float* ebuf = gcnt + G;     // pre path: [E,64] edge embeddings

  const size_t fixed_floats = (size_t)N * 64 * 4 + (size_t)G * 64 + G;
  const bool pre = (ws_size / 4 >= fixed_floats + (size_t)E * 64);

  const int nblk = (N + 3) / 4;                      // 4 node rows per block
  const int eblk = (E + 4 * EPW - 1) / (4 * EPW);    // 16 edges per block

  k_node_embed<<<nblk, 256, 0, stream>>>(x, ne_w, ne_b, ne_g, ne_be, h, N);
  if (pre)
    k_edge_embed<<<eblk, 256, 0, stream>>>(ea, ee_w, ee_b, ee_g, ee_be, ebuf, E);

  for (int l = 0; l < 2; ++l) {
    const float* Wl = msg_w + (size_t)l * 192 * 64;
    k_node_msgw<<<nblk, 256, 0, stream>>>(h, Wl, hw1, hw2, N);
    hipMemsetAsync(agg, 0, (size_t)N * 64 * sizeof(float), stream);
    if (pre) {
      k_edge_msg_pre<<<eblk, 256, 0, stream>>>(
          ebuf, Wl + 128 * 64, msg_b + l * 64, msg_g + l * 64, msg_be + l * 64,
          hw1, hw2, srcI, dstI, agg, E);
    } else {
      k_edge_msg_fb<<<eblk, 256, 0, stream>>>(
          ea, ee_w, ee_b, ee_g, ee_be,
          Wl + 128 * 64, msg_b + l * 64, msg_g + l * 64, msg_be + l * 64,
          hw1, hw2, srcI, dstI, agg, E);
    }
    k_node_update_ip<<<nblk, 256, 0, stream>>>(
        h, agg, upd_w + (size_t)l * 64 * 64,
        upd_b + l * 64, upd_g + l * 64, upd_be + l * 64,
        nrm_g + l * 64, nrm_be + l * 64, N);
  }

  hipMemsetAsync(gsum, 0, ((size_t)G * 64 + G) * sizeof(float), stream);
  k_pool<<<nblk, 256, 0, stream>>>(h, batch, gsum, gcnt, N);
  k_head<<<G, 64, 0, stream>>>(gsum, gcnt, h1_w, h1_b, h1_g, h1_be, h2_w, h2_b, out, G);
}

// Round 11
// 2142.507 us; speedup vs baseline: 1.0975x; 1.0975x over previous
//
#include <hip/hip_runtime.h>
#include <math.h>

// ---------- helpers ----------
__device__ __forceinline__ float wsum64(float v) {
#pragma unroll
  for (int m = 32; m > 0; m >>= 1) v += __shfl_xor(v, m, 64);
  return v;
}
__device__ __forceinline__ float silu_f(float x) { return x / (1.0f + __expf(-x)); }

// LayerNorm across a 64-lane wave (one value per lane), eps=1e-5
__device__ __forceinline__ float ln64(float v, float g, float b) {
  float s  = wsum64(v);
  float s2 = wsum64(v * v);
  float m   = s * 0.015625f;                       // /64
  float var = fmaxf(s2 * 0.015625f - m * m, 0.0f);
  return (v - m) * rsqrtf(var + 1e-5f) * g + b;
}

// ---------- node embedding: h = silu(LN(x @ ne_w + ne_b)) ----------
__global__ __launch_bounds__(256) void k_node_embed(
    const float* __restrict__ x, const float* __restrict__ W,
    const float* __restrict__ b, const float* __restrict__ g,
    const float* __restrict__ be, float* __restrict__ h, int n) {
  int row = (blockIdx.x * 256 + threadIdx.x) >> 6;
  int j = threadIdx.x & 63;
  if (row >= n) return;
  const float* xr = x + (size_t)row * 16;
  float acc = b[j];
#pragma unroll
  for (int k = 0; k < 16; k += 4) {
    float4 xv = *(const float4*)&xr[k];
    acc += xv.x * W[(k + 0) * 64 + j] + xv.y * W[(k + 1) * 64 + j] +
           xv.z * W[(k + 2) * 64 + j] + xv.w * W[(k + 3) * 64 + j];
  }
  float v = ln64(acc, g[j], be[j]);
  h[(size_t)row * 64 + j] = silu_f(v);
}

// ---------- edge embedding (ONCE, layer-independent): ebuf = silu(LN(ea@eeW)) ----------
__global__ __launch_bounds__(256) void k_edge_embed(
    const float* __restrict__ ea, const float* __restrict__ eeW,
    const float* __restrict__ eeB, const float* __restrict__ eeG,
    const float* __restrict__ eeBe, float* __restrict__ ebuf, int nedges) {
  __shared__ float sEA[4][32];         // per-wave 4 edges x 8 attrs

  const int wv = threadIdx.x >> 6;
  const int j  = threadIdx.x & 63;
  const int ebase = (blockIdx.x * 4 + wv) * 4;
  if (ebase >= nedges) return;

  if (j < 32) {
    long long gi = (long long)ebase * 8 + j;
    long long gmax = (long long)nedges * 8 - 1;
    if (gi > gmax) gi = gmax;
    sEA[wv][j] = ea[gi];               // same-wave write->read: ordered
  }

  float ewc[8];
#pragma unroll
  for (int k = 0; k < 8; ++k) ewc[k] = eeW[k * 64 + j];
  const float eb = eeB[j], eg = eeG[j], ebe = eeBe[j];

#pragma unroll
  for (int e = 0; e < 4; ++e) {
    const float* ar = &sEA[wv][e * 8];
    float ev = eb;
#pragma unroll
    for (int k = 0; k < 8; ++k) ev += ar[k] * ewc[k];
    ev = silu_f(ln64(ev, eg, ebe));
    if (ebase + e < nedges) ebuf[(size_t)(ebase + e) * 64 + j] = ev;
  }
}

// ---------- edge message: PERSISTENT grid-stride, pre-embedded edges ----------
// m = LN(silu(hw1[dst] + hw2[src] + e@W3 + msg_b)); agg[dst] += m
// W3 in LDS (staged once/block); e-rows staged coalesced with 1-iter software
// pipeline; gathers deferred to epilogue (MAC hides their latency).
#define EPW 4
__global__ __launch_bounds__(256) void k_edge_msg_p(
    const float* __restrict__ ebuf, const float* __restrict__ W3,
    const float* __restrict__ msgB, const float* __restrict__ msgG,
    const float* __restrict__ msgBe,
    const float* __restrict__ hw1, const float* __restrict__ hw2,
    const int* __restrict__ srcI, const int* __restrict__ dstI,
    float* __restrict__ agg, int nedges, int ngroups) {
  __shared__ float sW3[64 * 64];       // 16 KB
  __shared__ float sE[4][EPW][64];     // 4 KB

  for (int idx = threadIdx.x * 4; idx < 64 * 64; idx += 1024)
    *(float4*)&sW3[idx] = *(const float4*)&W3[idx];
  __syncthreads();                     // once per block

  const int wv = threadIdx.x >> 6;
  const int j  = threadIdx.x & 63;
  const int wstride = gridDim.x * 4;
  int g = blockIdx.x * 4 + wv;
  if (g >= ngroups) return;

  const float bj = msgB[j], mg = msgG[j], mbe = msgBe[j];
  const long long gmaxE = (long long)nedges * 64 - 4;

  // prologue: stage e-rows of first group (lane j -> edge j>>4, col (j&15)*4)
  {
    long long gi = (long long)g * (EPW * 64) + j * 4;
    if (gi > gmaxE) gi = gmaxE;
    float4 v = *(const float4*)&ebuf[gi];
    *(float4*)&sE[wv][j >> 4][(j & 15) * 4] = v;
  }

  for (; g < ngroups; g += wstride) {
    const int ebase = g * EPW;

    // issue next group's e-row load NOW (lands during MAC)
    int gn = g + wstride;
    if (gn >= ngroups) gn = g;
    long long gi = (long long)gn * (EPW * 64) + j * 4;
    if (gi > gmaxE) gi = gmaxE;
    float4 vnext = *(const float4*)&ebuf[gi];

    // issue gathers (results needed only in epilogue)
    int dI[EPW];
    float g1[EPW], g2[EPW];
#pragma unroll
    for (int e = 0; e < EPW; ++e) {
      int ce = min(ebase + e, nedges - 1);
      int s = srcI[ce];
      dI[e] = dstI[ce];
      g1[e] = hw1[(size_t)dI[e] * 64 + j];
      g2[e] = hw2[(size_t)s * 64 + j];
    }

    // MAC from LDS only
    float macc[EPW] = {0.f, 0.f, 0.f, 0.f};
#pragma unroll
    for (int k = 0; k < 64; k += 4) {
      float w0 = sW3[(k + 0) * 64 + j];
      float w1 = sW3[(k + 1) * 64 + j];
      float w2 = sW3[(k + 2) * 64 + j];
      float w3 = sW3[(k + 3) * 64 + j];
#pragma unroll
      for (int e = 0; e < EPW; ++e) {
        float4 ev4 = *(const float4*)&sE[wv][e][k];
        macc[e] += ev4.x * w0 + ev4.y * w1 + ev4.z * w2 + ev4.w * w3;
      }
    }

    // stage next group's rows (ds_write latency hides under epilogue)
    *(float4*)&sE[wv][j >> 4][(j & 15) * 4] = vnext;

    // epilogue: add gathers + bias, silu, LN, scatter
#pragma unroll
    for (int e = 0; e < EPW; ++e) {
      float m = ln64(silu_f(macc[e] + g1[e] + g2[e] + bj), mg, mbe);
      if (ebase + e < nedges) unsafeAtomicAdd(&agg[(size_t)dI[e] * 64 + j], m);
    }
  }
}

// ---------- edge message FALLBACK (ws too small): r9 proven kernel ----------
__global__ __launch_bounds__(256) void k_edge_msg_fb(
    const float* __restrict__ ea, const float* __restrict__ eeW,
    const float* __restrict__ eeB, const float* __restrict__ eeG,
    const float* __restrict__ eeBe,
    const float* __restrict__ W3, const float* __restrict__ msgB,
    const float* __restrict__ msgG, const float* __restrict__ msgBe,
    const float* __restrict__ hw1, const float* __restrict__ hw2,
    const int* __restrict__ srcI, const int* __restrict__ dstI,
    float* __restrict__ agg, int nedges) {
  __shared__ float sE[4][EPW][64];
  __shared__ float sEA[4][EPW * 8];

  const int wv = threadIdx.x >> 6;
  const int j  = threadIdx.x & 63;
  const int ebase = (blockIdx.x * 4 + wv) * EPW;
  if (ebase >= nedges) return;

  if (j < 32) {
    long long gi = (long long)ebase * 8 + j;
    long long gmax = (long long)nedges * 8 - 1;
    if (gi > gmax) gi = gmax;
    sEA[wv][j] = ea[gi];
  }

  const float bj = msgB[j];
  int dIdx[EPW];
  float acc[EPW];
#pragma unroll
  for (int e = 0; e < EPW; ++e) {
    int ce = min(ebase + e, nedges - 1);
    int s = srcI[ce];
    dIdx[e] = dstI[ce];
    acc[e] = hw1[(size_t)dIdx[e] * 64 + j] + hw2[(size_t)s * 64 + j] + bj;
  }
  {
    float ewc[8];
#pragma unroll
    for (int k = 0; k < 8; ++k) ewc[k] = eeW[k * 64 + j];
    const float eb = eeB[j], eg = eeG[j], ebe = eeBe[j];
#pragma unroll
    for (int e = 0; e < EPW; ++e) {
      const float* ar = &sEA[wv][e * 8];
      float ev = eb;
#pragma unroll
      for (int k = 0; k < 8; ++k) ev += ar[k] * ewc[k];
      ev = silu_f(ln64(ev, eg, ebe));
      sE[wv][e][j] = ev;
    }
  }
#pragma unroll
  for (int k = 0; k < 64; k += 4) {
    float w0 = W3[(k + 0) * 64 + j];
    float w1 = W3[(k + 1) * 64 + j];
    float w2 = W3[(k + 2) * 64 + j];
    float w3 = W3[(k + 3) * 64 + j];
#pragma unroll
    for (int e = 0; e < EPW; ++e) {
      float4 ev4 = *(const float4*)&sE[wv][e][k];
      acc[e] += ev4.x * w0 + ev4.y * w1 + ev4.z * w2 + ev4.w * w3;
    }
  }
  const float mg = msgG[j], mbe = msgBe[j];
#pragma unroll
  for (int e = 0; e < EPW; ++e) {
    float m = ln64(silu_f(acc[e]), mg, mbe);
    if (ebase + e < nedges) unsafeAtomicAdd(&agg[(size_t)dIdx[e] * 64 + j], m);
  }
}

// ---------- per-node msg weights: hw1 = h@W[0:64], hw2 = h@W[64:128] ----------
__global__ __launch_bounds__(256) void k_node_msgw(
    const float* __restrict__ h, const float* __restrict__ W,
    float* __restrict__ hw1, float* __restrict__ hw2, int n) {
  int row = (blockIdx.x * 256 + threadIdx.x) >> 6;
  int j = threadIdx.x & 63;
  if (row >= n) return;
  const float* hr = h + (size_t)row * 64;
  float a1 = 0.0f, a2 = 0.0f;
#pragma unroll
  for (int k = 0; k < 64; k += 4) {
    float4 hv = *(const float4*)&hr[k];
    a1 += hv.x * W[(k + 0) * 64 + j] + hv.y * W[(k + 1) * 64 + j] +
          hv.z * W[(k + 2) * 64 + j] + hv.w * W[(k + 3) * 64 + j];
    a2 += hv.x * W[(64 + k + 0) * 64 + j] + hv.y * W[(64 + k + 1) * 64 + j] +
          hv.z * W[(64 + k + 2) * 64 + j] + hv.w * W[(64 + k + 3) * 64 + j];
  }
  hw1[(size_t)row * 64 + j] = a1;
  hw2[(size_t)row * 64 + j] = a2;
}

// ---------- update IN-PLACE: h = LN(LN(silu((h+agg)@W+b)) + h) ----------
__global__ __launch_bounds__(256) void k_node_update_ip(
    float* h, const float* __restrict__ agg,
    const float* __restrict__ W, const float* __restrict__ b,
    const float* __restrict__ ug, const float* __restrict__ ube,
    const float* __restrict__ ng, const float* __restrict__ nbe, int n) {
  int row = (blockIdx.x * 256 + threadIdx.x) >> 6;
  int j = threadIdx.x & 63;
  if (row >= n) return;
  float* hr = h + (size_t)row * 64;
  const float* ar = agg + (size_t)row * 64;
  float acc = b[j];
  float hj = hr[j];
#pragma unroll
  for (int k = 0; k < 64; k += 4) {
    float4 hv = *(const float4*)&hr[k];
    float4 av = *(const float4*)&ar[k];
    acc += (hv.x + av.x) * W[(k + 0) * 64 + j] + (hv.y + av.y) * W[(k + 1) * 64 + j] +
           (hv.z + av.z) * W[(k + 2) * 64 + j] + (hv.w + av.w) * W[(k + 3) * 64 + j];
  }
  float u = ln64(silu_f(acc), ug[j], ube[j]);
  hr[j] = ln64(u + hj, ng[j], nbe[j]);
}

// ---------- pooling ----------
__global__ __launch_bounds__(256) void k_pool(
    const float* __restrict__ h, const int* __restrict__ batch,
    float* __restrict__ gsum, float* __restrict__ gcnt, int n) {
  int row = (blockIdx.x * 256 + threadIdx.x) >> 6;
  int j = threadIdx.x & 63;
  if (row >= n) return;
  int b = batch[row];
  unsafeAtomicAdd(&gsum[(size_t)b * 64 + j], h[(size_t)row * 64 + j]);
  if (j == 0) unsafeAtomicAdd(&gcnt[b], 1.0f);
}

// ---------- head: out = silu(LN(g@h1_w+b)) @ h2_w + h2_b ----------
__global__ __launch_bounds__(64) void k_head(
    const float* __restrict__ gsum, const float* __restrict__ gcnt,
    const float* __restrict__ w1, const float* __restrict__ b1,
    const float* __restrict__ g1, const float* __restrict__ be1,
    const float* __restrict__ w2, const float* __restrict__ b2,
    float* __restrict__ out, int ngraphs) {
  int gidx = blockIdx.x;
  int j = threadIdx.x;
  if (gidx >= ngraphs) return;
  __shared__ float sg[64];
  float cnt = fmaxf(gcnt[gidx], 1.0f);
  sg[j] = gsum[(size_t)gidx * 64 + j] / cnt;
  float acc = 0.0f;
  if (j < 32) {
    acc = b1[j];
#pragma unroll 8
    for (int k = 0; k < 64; ++k) acc += sg[k] * w1[k * 32 + j];
  }
  float s = acc, s2 = acc * acc;
#pragma unroll
  for (int m = 16; m > 0; m >>= 1) {
    s  += __shfl_xor(s,  m, 64);
    s2 += __shfl_xor(s2, m, 64);
  }
  float mean = s * 0.03125f;
  float var  = fmaxf(s2 * 0.03125f - mean * mean, 0.0f);
  float z = 0.0f;
  if (j < 32) {
    float nv = (acc - mean) * rsqrtf(var + 1e-5f) * g1[j] + be1[j];
    z = silu_f(nv) * w2[j];
  }
  float tot = wsum64(z);
  if (j == 0) out[gidx] = tot + b2[0];
}

// ---------- launch ----------
extern "C" void kernel_launch(void* const* d_in, const int* in_sizes, int n_in,
                              void* d_out, int out_size, void* d_ws, size_t ws_size,
                              hipStream_t stream) {
  const float* x      = (const float*)d_in[0];
  const float* ea     = (const float*)d_in[1];
  const float* ne_w   = (const float*)d_in[2];
  const float* ne_b   = (const float*)d_in[3];
  const float* ne_g   = (const float*)d_in[4];
  const float* ne_be  = (const float*)d_in[5];
  const float* ee_w   = (const float*)d_in[6];
  const float* ee_b   = (const float*)d_in[7];
  const float* ee_g   = (const float*)d_in[8];
  const float* ee_be  = (const float*)d_in[9];
  const float* msg_w  = (const float*)d_in[10];
  const float* msg_b  = (const float*)d_in[11];
  const float* msg_g  = (const float*)d_in[12];
  const float* msg_be = (const float*)d_in[13];
  const float* upd_w  = (const float*)d_in[14];
  const float* upd_b  = (const float*)d_in[15];
  const float* upd_g  = (const float*)d_in[16];
  const float* upd_be = (const float*)d_in[17];
  const float* nrm_g  = (const float*)d_in[18];
  const float* nrm_be = (const float*)d_in[19];
  const float* h1_w   = (const float*)d_in[20];
  const float* h1_b   = (const float*)d_in[21];
  const float* h1_g   = (const float*)d_in[22];
  const float* h1_be  = (const float*)d_in[23];
  const float* h2_w   = (const float*)d_in[24];
  const float* h2_b   = (const float*)d_in[25];
  const int*   ei     = (const int*)d_in[26];
  const int*   batch  = (const int*)d_in[27];
  float* out = (float*)d_out;

  const int N = in_sizes[0] / 16;
  const int E = in_sizes[1] / 8;
  const int G = out_size;
  const int* srcI = ei;       // edge_index[0] = src (x_j)
  const int* dstI = ei + E;   // edge_index[1] = dst (x_i)

  float* ws  = (float*)d_ws;
  float* h    = ws;
  float* hw1  = h   + (size_t)N * 64;
  float* hw2  = hw1 + (size_t)N * 64;
  float* agg  = hw2 + (size_t)N * 64;
  float* gsum = agg + (size_t)N * 64;
  float* gcnt = gsum + (size_t)G * 64;
  float* ebuf = gcnt + G;     // pre path: [E,64] edge embeddings

  const size_t fixed_floats = (size_t)N * 64 * 4 + (size_t)G * 64 + G;
  const bool pre = (ws_size / 4 >= fixed_floats + (size_t)E * 64);

  const int nblk = (N + 3) / 4;                      // 4 node rows per block
  const int eblk = (E + 4 * EPW - 1) / (4 * EPW);    // 16 edges per block
  const int ngroups = (E + EPW - 1) / EPW;
  int pblk = (ngroups + 3) / 4;
  if (pblk > 1024) pblk = 1024;                      // persistent: ~4 blocks/CU

  k_node_embed<<<nblk, 256, 0, stream>>>(x, ne_w, ne_b, ne_g, ne_be, h, N);
  if (pre)
    k_edge_embed<<<eblk, 256, 0, stream>>>(ea, ee_w, ee_b, ee_g, ee_be, ebuf, E);

  for (int l = 0; l < 2; ++l) {
    const float* Wl = msg_w + (size_t)l * 192 * 64;
    k_node_msgw<<<nblk, 256, 0, stream>>>(h, Wl, hw1, hw2, N);
    hipMemsetAsync(agg, 0, (size_t)N * 64 * sizeof(float), stream);
    if (pre) {
      k_edge_msg_p<<<pblk, 256, 0, stream>>>(
          ebuf, Wl + 128 * 64, msg_b + l * 64, msg_g + l * 64, msg_be + l * 64,
          hw1, hw2, srcI, dstI, agg, E, ngroups);
    } else {
      k_edge_msg_fb<<<eblk, 256, 0, stream>>>(
          ea, ee_w, ee_b, ee_g, ee_be,
          Wl + 128 * 64, msg_b + l * 64, msg_g + l * 64, msg_be + l * 64,
          hw1, hw2, srcI, dstI, agg, E);
    }
    k_node_update_ip<<<nblk, 256, 0, stream>>>(
        h, agg, upd_w + (size_t)l * 64 * 64,
        upd_b + l * 64, upd_g + l * 64, upd_be + l * 64,
        nrm_g + l * 64, nrm_be + l * 64, N);
  }

  hipMemsetAsync(gsum, 0, ((size_t)G * 64 + G) * sizeof(float), stream);
  k_pool<<<nblk, 256, 0, stream>>>(h, batch, gsum, gcnt, N);
  k_head<<<G, 64, 0, stream>>>(gsum, gcnt, h1_w, h1_b, h1_g, h1_be, h2_w, h2_b, out, G);
}

// Round 12
// 1259.454 us; speedup vs baseline: 1.8671x; 1.7011x over previous
//
#include <hip/hip_runtime.h>
#include <math.h>

// ---------- helpers ----------
__device__ __forceinline__ float wsum64(float v) {
#pragma unroll
  for (int m = 32; m > 0; m >>= 1) v += __shfl_xor(v, m, 64);
  return v;
}
__device__ __forceinline__ float silu_f(float x) { return x / (1.0f + __expf(-x)); }

// LayerNorm across a 64-lane wave; two reduce chains explicitly interleaved
__device__ __forceinline__ float ln64(float v, float g, float b) {
  float s = v, s2 = v * v;
#pragma unroll
  for (int m = 32; m > 0; m >>= 1) {
    s  += __shfl_xor(s,  m, 64);
    s2 += __shfl_xor(s2, m, 64);
  }
  float mean = s * 0.015625f;
  float var  = fmaxf(s2 * 0.015625f - mean * mean, 0.0f);
  return (v - mean) * rsqrtf(var + 1e-5f) * g + b;
}

// ---------- node embedding: h = silu(LN(x @ ne_w + ne_b)) ----------
__global__ __launch_bounds__(256) void k_node_embed(
    const float* __restrict__ x, const float* __restrict__ W,
    const float* __restrict__ b, const float* __restrict__ g,
    const float* __restrict__ be, float* __restrict__ h, int n) {
  int row = (blockIdx.x * 256 + threadIdx.x) >> 6;
  int j = threadIdx.x & 63;
  if (row >= n) return;
  const float* xr = x + (size_t)row * 16;
  float acc = b[j];
#pragma unroll
  for (int k = 0; k < 16; k += 4) {
    float4 xv = *(const float4*)&xr[k];
    acc += xv.x * W[(k + 0) * 64 + j] + xv.y * W[(k + 1) * 64 + j] +
           xv.z * W[(k + 2) * 64 + j] + xv.w * W[(k + 3) * 64 + j];
  }
  float v = ln64(acc, g[j], be[j]);
  h[(size_t)row * 64 + j] = silu_f(v);
}

// ---------- edge embedding (ONCE, layer-independent): ebuf = silu(LN(ea@eeW)) ----------
__global__ __launch_bounds__(256) void k_edge_embed(
    const float* __restrict__ ea, const float* __restrict__ eeW,
    const float* __restrict__ eeB, const float* __restrict__ eeG,
    const float* __restrict__ eeBe, float* __restrict__ ebuf, int nedges) {
  __shared__ float sEA[4][32];         // per-wave 4 edges x 8 attrs

  const int wv = threadIdx.x >> 6;
  const int j  = threadIdx.x & 63;
  const int ebase = (blockIdx.x * 4 + wv) * 4;
  if (ebase >= nedges) return;

  if (j < 32) {
    long long gi = (long long)ebase * 8 + j;
    long long gmax = (long long)nedges * 8 - 1;
    if (gi > gmax) gi = gmax;
    sEA[wv][j] = ea[gi];               // same-wave write->read: ordered
  }

  float ewc[8];
#pragma unroll
  for (int k = 0; k < 8; ++k) ewc[k] = eeW[k * 64 + j];
  const float eb = eeB[j], eg = eeG[j], ebe = eeBe[j];

#pragma unroll
  for (int e = 0; e < 4; ++e) {
    const float* ar = &sEA[wv][e * 8];
    float ev = eb;
#pragma unroll
    for (int k = 0; k < 8; ++k) ev += ar[k] * ewc[k];
    ev = silu_f(ln64(ev, eg, ebe));
    if (ebase + e < nedges) ebuf[(size_t)(ebase + e) * 64 + j] = ev;
  }
}

// ---------- edge message (r9 structure + pre-embedded edges) ----------
// m = LN(silu(hw1[dst] + hw2[src] + e@W3 + msg_b)); agg[dst] += m
// e-rows staged coalesced from ebuf (float4/lane); W3 direct global (L1);
// gathers issued first, consumed only in epilogue (MAC hides latency).
#define EPW 4
__global__ __launch_bounds__(256) void k_edge_msg_pre2(
    const float* __restrict__ ebuf, const float* __restrict__ W3,
    const float* __restrict__ msgB, const float* __restrict__ msgG,
    const float* __restrict__ msgBe,
    const float* __restrict__ hw1, const float* __restrict__ hw2,
    const int* __restrict__ srcI, const int* __restrict__ dstI,
    float* __restrict__ agg, int nedges) {
  __shared__ float sE[4][EPW][64];     // 4 KB

  const int wv = threadIdx.x >> 6;
  const int j  = threadIdx.x & 63;
  const int ebase = (blockIdx.x * 4 + wv) * EPW;
  if (ebase >= nedges) return;

  // coalesced e-row staging: lane j -> edge (j>>4), cols (j&15)*4 .. +3
  {
    long long gi = (long long)ebase * 64 + j * 4;
    long long gmax = (long long)nedges * 64 - 4;
    if (gi > gmax) gi = gmax;          // tail lanes load garbage; discarded
    float4 v = *(const float4*)&ebuf[gi];
    *(float4*)&sE[wv][j >> 4][(j & 15) * 4] = v;   // same-wave: ordered
  }

  // gathers issued up-front; results not needed until epilogue
  int dIdx[EPW];
  float g1[EPW], g2[EPW];
#pragma unroll
  for (int e = 0; e < EPW; ++e) {
    int ce = min(ebase + e, nedges - 1);
    int s = srcI[ce];
    dIdx[e] = dstI[ce];
    g1[e] = hw1[(size_t)dIdx[e] * 64 + j];
    g2[e] = hw2[(size_t)s * 64 + j];
  }

  // MAC from LDS + L1-resident W3
  float macc[EPW] = {0.f, 0.f, 0.f, 0.f};
#pragma unroll
  for (int k = 0; k < 64; k += 4) {
    float w0 = W3[(k + 0) * 64 + j];
    float w1 = W3[(k + 1) * 64 + j];
    float w2 = W3[(k + 2) * 64 + j];
    float w3 = W3[(k + 3) * 64 + j];
#pragma unroll
    for (int e = 0; e < EPW; ++e) {
      float4 ev4 = *(const float4*)&sE[wv][e][k];
      macc[e] += ev4.x * w0 + ev4.y * w1 + ev4.z * w2 + ev4.w * w3;
    }
  }

  // epilogue: fold gathers + bias, silu, LN, scatter-add
  const float bj = msgB[j], mg = msgG[j], mbe = msgBe[j];
#pragma unroll
  for (int e = 0; e < EPW; ++e) {
    float m = ln64(silu_f(macc[e] + g1[e] + g2[e] + bj), mg, mbe);
    if (ebase + e < nedges) unsafeAtomicAdd(&agg[(size_t)dIdx[e] * 64 + j], m);
  }
}

// ---------- edge message FALLBACK (ws too small): r9 proven kernel ----------
__global__ __launch_bounds__(256) void k_edge_msg_fb(
    const float* __restrict__ ea, const float* __restrict__ eeW,
    const float* __restrict__ eeB, const float* __restrict__ eeG,
    const float* __restrict__ eeBe,
    const float* __restrict__ W3, const float* __restrict__ msgB,
    const float* __restrict__ msgG, const float* __restrict__ msgBe,
    const float* __restrict__ hw1, const float* __restrict__ hw2,
    const int* __restrict__ srcI, const int* __restrict__ dstI,
    float* __restrict__ agg, int nedges) {
  __shared__ float sE[4][EPW][64];
  __shared__ float sEA[4][EPW * 8];

  const int wv = threadIdx.x >> 6;
  const int j  = threadIdx.x & 63;
  const int ebase = (blockIdx.x * 4 + wv) * EPW;
  if (ebase >= nedges) return;

  if (j < 32) {
    long long gi = (long long)ebase * 8 + j;
    long long gmax = (long long)nedges * 8 - 1;
    if (gi > gmax) gi = gmax;
    sEA[wv][j] = ea[gi];
  }

  const float bj = msgB[j];
  int dIdx[EPW];
  float acc[EPW];
#pragma unroll
  for (int e = 0; e < EPW; ++e) {
    int ce = min(ebase + e, nedges - 1);
    int s = srcI[ce];
    dIdx[e] = dstI[ce];
    acc[e] = hw1[(size_t)dIdx[e] * 64 + j] + hw2[(size_t)s * 64 + j] + bj;
  }
  {
    float ewc[8];
#pragma unroll
    for (int k = 0; k < 8; ++k) ewc[k] = eeW[k * 64 + j];
    const float eb = eeB[j], eg = eeG[j], ebe = eeBe[j];
#pragma unroll
    for (int e = 0; e < EPW; ++e) {
      const float* ar = &sEA[wv][e * 8];
      float ev = eb;
#pragma unroll
      for (int k = 0; k < 8; ++k) ev += ar[k] * ewc[k];
      ev = silu_f(ln64(ev, eg, ebe));
      sE[wv][e][j] = ev;
    }
  }
#pragma unroll
  for (int k = 0; k < 64; k += 4) {
    float w0 = W3[(k + 0) * 64 + j];
    float w1 = W3[(k + 1) * 64 + j];
    float w2 = W3[(k + 2) * 64 + j];
    float w3 = W3[(k + 3) * 64 + j];
#pragma unroll
    for (int e = 0; e < EPW; ++e) {
      float4 ev4 = *(const float4*)&sE[wv][e][k];
      acc[e] += ev4.x * w0 + ev4.y * w1 + ev4.z * w2 + ev4.w * w3;
    }
  }
  const float mg = msgG[j], mbe = msgBe[j];
#pragma unroll
  for (int e = 0; e < EPW; ++e) {
    float m = ln64(silu_f(acc[e]), mg, mbe);
    if (ebase + e < nedges) unsafeAtomicAdd(&agg[(size_t)dIdx[e] * 64 + j], m);
  }
}

// ---------- per-node msg weights: hw1 = h@W[0:64], hw2 = h@W[64:128] ----------
__global__ __launch_bounds__(256) void k_node_msgw(
    const float* __restrict__ h, const float* __restrict__ W,
    float* __restrict__ hw1, float* __restrict__ hw2, int n) {
  int row = (blockIdx.x * 256 + threadIdx.x) >> 6;
  int j = threadIdx.x & 63;
  if (row >= n) return;
  const float* hr = h + (size_t)row * 64;
  float a1 = 0.0f, a2 = 0.0f;
#pragma unroll
  for (int k = 0; k < 64; k += 4) {
    float4 hv = *(const float4*)&hr[k];
    a1 += hv.x * W[(k + 0) * 64 + j] + hv.y * W[(k + 1) * 64 + j] +
          hv.z * W[(k + 2) * 64 + j] + hv.w * W[(k + 3) * 64 + j];
    a2 += hv.x * W[(64 + k + 0) * 64 + j] + hv.y * W[(64 + k + 1) * 64 + j] +
          hv.z * W[(64 + k + 2) * 64 + j] + hv.w * W[(64 + k + 3) * 64 + j];
  }
  hw1[(size_t)row * 64 + j] = a1;
  hw2[(size_t)row * 64 + j] = a2;
}

// ---------- update IN-PLACE: h = LN(LN(silu((h+agg)@W+b)) + h) ----------
__global__ __launch_bounds__(256) void k_node_update_ip(
    float* h, const float* __restrict__ agg,
    const float* __restrict__ W, const float* __restrict__ b,
    const float* __restrict__ ug, const float* __restrict__ ube,
    const float* __restrict__ ng, const float* __restrict__ nbe, int n) {
  int row = (blockIdx.x * 256 + threadIdx.x) >> 6;
  int j = threadIdx.x & 63;
  if (row >= n) return;
  float* hr = h + (size_t)row * 64;
  const float* ar = agg + (size_t)row * 64;
  float acc = b[j];
  float hj = hr[j];
#pragma unroll
  for (int k = 0; k < 64; k += 4) {
    float4 hv = *(const float4*)&hr[k];
    float4 av = *(const float4*)&ar[k];
    acc += (hv.x + av.x) * W[(k + 0) * 64 + j] + (hv.y + av.y) * W[(k + 1) * 64 + j] +
           (hv.z + av.z) * W[(k + 2) * 64 + j] + (hv.w + av.w) * W[(k + 3) * 64 + j];
  }
  float u = ln64(silu_f(acc), ug[j], ube[j]);
  hr[j] = ln64(u + hj, ng[j], nbe[j]);
}

// ---------- pooling ----------
__global__ __launch_bounds__(256) void k_pool(
    const float* __restrict__ h, const int* __restrict__ batch,
    float* __restrict__ gsum, float* __restrict__ gcnt, int n) {
  int row = (blockIdx.x * 256 + threadIdx.x) >> 6;
  int j = threadIdx.x & 63;
  if (row >= n) return;
  int b = batch[row];
  unsafeAtomicAdd(&gsum[(size_t)b * 64 + j], h[(size_t)row * 64 + j]);
  if (j == 0) unsafeAtomicAdd(&gcnt[b], 1.0f);
}

// ---------- head: out = silu(LN(g@h1_w+b)) @ h2_w + h2_b ----------
__global__ __launch_bounds__(64) void k_head(
    const float* __restrict__ gsum, const float* __restrict__ gcnt,
    const float* __restrict__ w1, const float* __restrict__ b1,
    const float* __restrict__ g1, const float* __restrict__ be1,
    const float* __restrict__ w2, const float* __restrict__ b2,
    float* __restrict__ out, int ngraphs) {
  int gidx = blockIdx.x;
  int j = threadIdx.x;
  if (gidx >= ngraphs) return;
  __shared__ float sg[64];
  float cnt = fmaxf(gcnt[gidx], 1.0f);
  sg[j] = gsum[(size_t)gidx * 64 + j] / cnt;
  float acc = 0.0f;
  if (j < 32) {
    acc = b1[j];
#pragma unroll 8
    for (int k = 0; k < 64; ++k) acc += sg[k] * w1[k * 32 + j];
  }
  float s = acc, s2 = acc * acc;
#pragma unroll
  for (int m = 16; m > 0; m >>= 1) {
    s  += __shfl_xor(s,  m, 64);
    s2 += __shfl_xor(s2, m, 64);
  }
  float mean = s * 0.03125f;
  float var  = fmaxf(s2 * 0.03125f - mean * mean, 0.0f);
  float z = 0.0f;
  if (j < 32) {
    float nv = (acc - mean) * rsqrtf(var + 1e-5f) * g1[j] + be1[j];
    z = silu_f(nv) * w2[j];
  }
  float tot = wsum64(z);
  if (j == 0) out[gidx] = tot + b2[0];
}

// ---------- launch ----------
extern "C" void kernel_launch(void* const* d_in, const int* in_sizes, int n_in,
                              void* d_out, int out_size, void* d_ws, size_t ws_size,
                              hipStream_t stream) {
  const float* x      = (const float*)d_in[0];
  const float* ea     = (const float*)d_in[1];
  const float* ne_w   = (const float*)d_in[2];
  const float* ne_b   = (const float*)d_in[3];
  const float* ne_g   = (const float*)d_in[4];
  const float* ne_be  = (const float*)d_in[5];
  const float* ee_w   = (const float*)d_in[6];
  const float* ee_b   = (const float*)d_in[7];
  const float* ee_g   = (const float*)d_in[8];
  const float* ee_be  = (const float*)d_in[9];
  const float* msg_w  = (const float*)d_in[10];
  const float* msg_b  = (const float*)d_in[11];
  const float* msg_g  = (const float*)d_in[12];
  const float* msg_be = (const float*)d_in[13];
  const float* upd_w  = (const float*)d_in[14];
  const float* upd_b  = (const float*)d_in[15];
  const float* upd_g  = (const float*)d_in[16];
  const float* upd_be = (const float*)d_in[17];
  const float* nrm_g  = (const float*)d_in[18];
  const float* nrm_be = (const float*)d_in[19];
  const float* h1_w   = (const float*)d_in[20];
  const float* h1_b   = (const float*)d_in[21];
  const float* h1_g   = (const float*)d_in[22];
  const float* h1_be  = (const float*)d_in[23];
  const float* h2_w   = (const float*)d_in[24];
  const float* h2_b   = (const float*)d_in[25];
  const int*   ei     = (const int*)d_in[26];
  const int*   batch  = (const int*)d_in[27];
  float* out = (float*)d_out;

  const int N = in_sizes[0] / 16;
  const int E = in_sizes[1] / 8;
  const int G = out_size;
  const int* srcI = ei;       // edge_index[0] = src (x_j)
  const int* dstI = ei + E;   // edge_index[1] = dst (x_i)

  float* ws  = (float*)d_ws;
  float* h    = ws;
  float* hw1  = h   + (size_t)N * 64;
  float* hw2  = hw1 + (size_t)N * 64;
  float* agg  = hw2 + (size_t)N * 64;
  float* gsum = agg + (size_t)N * 64;
  float* gcnt = gsum + (size_t)G * 64;
  float* ebuf = gcnt + G;     // pre path: [E,64] edge embeddings

  const size_t fixed_floats = (size_t)N * 64 * 4 + (size_t)G * 64 + G;
  const bool pre = (ws_size / 4 >= fixed_floats + (size_t)E * 64);

  const int nblk = (N + 3) / 4;                      // 4 node rows per block
  const int eblk = (E + 4 * EPW - 1) / (4 * EPW);    // 16 edges per block

  k_node_embed<<<nblk, 256, 0, stream>>>(x, ne_w, ne_b, ne_g, ne_be, h, N);
  if (pre)
    k_edge_embed<<<eblk, 256, 0, stream>>>(ea, ee_w, ee_b, ee_g, ee_be, ebuf, E);

  for (int l = 0; l < 2; ++l) {
    const float* Wl = msg_w + (size_t)l * 192 * 64;
    k_node_msgw<<<nblk, 256, 0, stream>>>(h, Wl, hw1, hw2, N);
    hipMemsetAsync(agg, 0, (size_t)N * 64 * sizeof(float), stream);
    if (pre) {
      k_edge_msg_pre2<<<eblk, 256, 0, stream>>>(
          ebuf, Wl + 128 * 64, msg_b + l * 64, msg_g + l * 64, msg_be + l * 64,
          hw1, hw2, srcI, dstI, agg, E);
    } else {
      k_edge_msg_fb<<<eblk, 256, 0, stream>>>(
          ea, ee_w, ee_b, ee_g, ee_be,
          Wl + 128 * 64, msg_b + l * 64, msg_g + l * 64, msg_be + l * 64,
          hw1, hw2, srcI, dstI, agg, E);
    }
    k_node_update_ip<<<nblk, 256, 0, stream>>>(
        h, agg, upd_w + (size_t)l * 64 * 64,
        upd_b + l * 64, upd_g + l * 64, upd_be + l * 64,
        nrm_g + l * 64, nrm_be + l * 64, N);
  }

  hipMemsetAsync(gsum, 0, ((size_t)G * 64 + G) * sizeof(float), stream);
  k_pool<<<nblk, 256, 0, stream>>>(h, batch, gsum, gcnt, N);
  k_head<<<G, 64, 0, stream>>>(gsum, gcnt, h1_w, h1_b, h1_g, h1_be, h2_w, h2_b, out, G);
}